// Round 4
// baseline (385.603 us; speedup 1.0000x reference)
//
#include <hip/hip_runtime.h>

#define PN 100000
#define NCB 782      // ceil(PN/128)
#define CAP 4096

typedef _Float16 f16;
typedef _Float16 f16x8 __attribute__((ext_vector_type(8)));
typedef float f32x4 __attribute__((ext_vector_type(4)));

__device__ __forceinline__ unsigned int sortkey(float f) {
    unsigned int u = __float_as_uint(f);
    return u ^ ((u & 0x80000000u) ? 0xFFFFFFFFu : 0x80000000u);
}

__device__ __forceinline__ void gload_lds16(const void* g, void* l) {
    __builtin_amdgcn_global_load_lds((const __attribute__((address_space(1))) void*)g,
                                     (__attribute__((address_space(3))) void*)l, 16, 0, 0);
}

// ---------------- k1 layers: Y[256][N] = relu(X[256][K] @ W[K][N] + b) ----------------
__global__ __launch_bounds__(256) void k1_layer(
    const float* __restrict__ X, const float* __restrict__ W,
    const float* __restrict__ bias, float* __restrict__ Y,
    int N, int K)
{
    __shared__ __align__(16) float As[64][36];
    __shared__ __align__(16) float Bs[64][68];
    int t = threadIdx.x;
    int cbase = blockIdx.x * 64;
    int rbase = blockIdx.y * 32;
    int tx = t & 15, ty = t >> 4;
    float acc[2][4] = {};

    for (int kt = 0; kt < K; kt += 64) {
        #pragma unroll
        for (int i = 0; i < 2; ++i) {
            int e = i * 256 + t;
            int r = e >> 4, k4 = e & 15;
            float4 v = *(const float4*)&X[(size_t)(rbase + r) * K + kt + k4 * 4];
            As[k4 * 4 + 0][r] = v.x; As[k4 * 4 + 1][r] = v.y;
            As[k4 * 4 + 2][r] = v.z; As[k4 * 4 + 3][r] = v.w;
        }
        #pragma unroll
        for (int i = 0; i < 4; ++i) {
            int e = i * 256 + t;
            int k = e >> 4, c4 = e & 15;
            *(float4*)&Bs[k][c4 * 4] = *(const float4*)&W[(size_t)(kt + k) * N + cbase + c4 * 4];
        }
        __syncthreads();
        #pragma unroll 8
        for (int k = 0; k < 64; ++k) {
            float2 av = *(const float2*)&As[k][ty * 2];
            float4 bv = *(const float4*)&Bs[k][tx * 4];
            acc[0][0] = fmaf(av.x, bv.x, acc[0][0]); acc[0][1] = fmaf(av.x, bv.y, acc[0][1]);
            acc[0][2] = fmaf(av.x, bv.z, acc[0][2]); acc[0][3] = fmaf(av.x, bv.w, acc[0][3]);
            acc[1][0] = fmaf(av.y, bv.x, acc[1][0]); acc[1][1] = fmaf(av.y, bv.y, acc[1][1]);
            acc[1][2] = fmaf(av.y, bv.z, acc[1][2]); acc[1][3] = fmaf(av.y, bv.w, acc[1][3]);
        }
        __syncthreads();
    }
    #pragma unroll
    for (int i = 0; i < 2; ++i) {
        int row = rbase + ty * 2 + i;
        #pragma unroll
        for (int j = 0; j < 4; ++j) {
            int col = cbase + tx * 4 + j;
            Y[(size_t)row * N + col] = fmaxf(acc[i][j] + bias[col], 0.f);
        }
    }
}

// ---------------- k1 final: ang[256][64] = normalize(X @ W[512][64] + b) ----------------
__global__ __launch_bounds__(256) void k1_final(
    const float* __restrict__ X, const float* __restrict__ W,
    const float* __restrict__ bias, float* __restrict__ ang)
{
    __shared__ __align__(16) float As[64][36];
    __shared__ __align__(16) float Bs[64][68];
    int t = threadIdx.x;
    int rbase = blockIdx.x * 32;
    int tx = t & 15, ty = t >> 4;
    float acc[2][4] = {};

    for (int kt = 0; kt < 512; kt += 64) {
        #pragma unroll
        for (int i = 0; i < 2; ++i) {
            int e = i * 256 + t;
            int r = e >> 4, k4 = e & 15;
            float4 v = *(const float4*)&X[(size_t)(rbase + r) * 512 + kt + k4 * 4];
            As[k4 * 4 + 0][r] = v.x; As[k4 * 4 + 1][r] = v.y;
            As[k4 * 4 + 2][r] = v.z; As[k4 * 4 + 3][r] = v.w;
        }
        #pragma unroll
        for (int i = 0; i < 4; ++i) {
            int e = i * 256 + t;
            int k = e >> 4, c4 = e & 15;
            *(float4*)&Bs[k][c4 * 4] = *(const float4*)&W[(size_t)(kt + k) * 64 + c4 * 4];
        }
        __syncthreads();
        #pragma unroll 8
        for (int k = 0; k < 64; ++k) {
            float2 av = *(const float2*)&As[k][ty * 2];
            float4 bv = *(const float4*)&Bs[k][tx * 4];
            acc[0][0] = fmaf(av.x, bv.x, acc[0][0]); acc[0][1] = fmaf(av.x, bv.y, acc[0][1]);
            acc[0][2] = fmaf(av.x, bv.z, acc[0][2]); acc[0][3] = fmaf(av.x, bv.w, acc[0][3]);
            acc[1][0] = fmaf(av.y, bv.x, acc[1][0]); acc[1][1] = fmaf(av.y, bv.y, acc[1][1]);
            acc[1][2] = fmaf(av.y, bv.z, acc[1][2]); acc[1][3] = fmaf(av.y, bv.w, acc[1][3]);
        }
        __syncthreads();
    }
    #pragma unroll
    for (int i = 0; i < 2; ++i) {
        float v[4];
        float ss = 0.f;
        #pragma unroll
        for (int j = 0; j < 4; ++j) {
            v[j] = acc[i][j] + bias[tx * 4 + j];
            ss = fmaf(v[j], v[j], ss);
        }
        ss += __shfl_xor(ss, 1); ss += __shfl_xor(ss, 2);
        ss += __shfl_xor(ss, 4); ss += __shfl_xor(ss, 8);
        float inv = 1.0f / (sqrtf(ss) + 1e-5f);
        int row = rbase + ty * 2 + i;
        #pragma unroll
        for (int j = 0; j < 4; ++j)
            ang[(size_t)row * 64 + tx * 4 + j] = v[j] * inv;
    }
}

// ---------------- K2v2: logits + per-row expsum partials + 8-bin hist ----------------
// 128x128 tile, 8x8 micro. As[k][row] stride 129; Bs[k][col + col/8] stride 145.
__global__ __launch_bounds__(256) void k2v2(
    const float* __restrict__ ang, const float* __restrict__ ap,
    float* __restrict__ logits, unsigned int* __restrict__ ghist,
    float* __restrict__ gsum)
{
    __shared__ __align__(16) float As[64 * 129];
    __shared__ __align__(16) float Bs[64 * 145];
    int t = threadIdx.x;
    int bx = blockIdx.x;
    int rbase = blockIdx.y * 128;
    int cbase = bx * 128;
    int tx = t & 15, ty = t >> 4;

    #pragma unroll
    for (int i = 0; i < 8; ++i) {
        int e = i * 256 + t;
        int row = e >> 4, k4 = e & 15;
        float4 v = *(const float4*)&ang[(size_t)(rbase + row) * 64 + k4 * 4];
        As[(k4 * 4 + 0) * 129 + row] = v.x;
        As[(k4 * 4 + 1) * 129 + row] = v.y;
        As[(k4 * 4 + 2) * 129 + row] = v.z;
        As[(k4 * 4 + 3) * 129 + row] = v.w;
    }
    #pragma unroll
    for (int i = 0; i < 8; ++i) {
        int e = i * 256 + t;
        int col = e >> 4, k4 = e & 15;
        int gc = cbase + col;
        float4 v = make_float4(0.f, 0.f, 0.f, 0.f);
        if (gc < PN) v = *(const float4*)&ap[(size_t)gc * 64 + k4 * 4];
        int cc = col + (col >> 3);
        Bs[(k4 * 4 + 0) * 145 + cc] = v.x;
        Bs[(k4 * 4 + 1) * 145 + cc] = v.y;
        Bs[(k4 * 4 + 2) * 145 + cc] = v.z;
        Bs[(k4 * 4 + 3) * 145 + cc] = v.w;
    }
    __syncthreads();

    float acc[8][8] = {};
    #pragma unroll 2
    for (int k = 0; k < 64; ++k) {
        float av[8], bv[8];
        *(float4*)&av[0] = *(const float4*)&As[k * 129 + ty * 8];
        *(float4*)&av[4] = *(const float4*)&As[k * 129 + ty * 8 + 4];
        *(float4*)&bv[0] = *(const float4*)&Bs[k * 145 + tx * 9];
        *(float4*)&bv[4] = *(const float4*)&Bs[k * 145 + tx * 9 + 4];
        #pragma unroll
        for (int i = 0; i < 8; ++i)
            #pragma unroll
            for (int j = 0; j < 8; ++j)
                acc[i][j] = fmaf(av[i], bv[j], acc[i][j]);
    }

    // write logits
    bool full = (cbase + 128 <= PN);
    #pragma unroll
    for (int i = 0; i < 8; ++i) {
        size_t rowoff = (size_t)(rbase + ty * 8 + i) * PN;
        int gc0 = cbase + tx * 8;
        if (full) {
            *(float4*)&logits[rowoff + gc0] = make_float4(acc[i][0], acc[i][1], acc[i][2], acc[i][3]);
            *(float4*)&logits[rowoff + gc0 + 4] = make_float4(acc[i][4], acc[i][5], acc[i][6], acc[i][7]);
        } else {
            for (int j = 0; j < 8; ++j)
                if (gc0 + j < PN) logits[rowoff + gc0 + j] = acc[i][j];
        }
    }

    // epilogue: hist + exp partials (overlay on As/Bs)
    __syncthreads();
    unsigned int* hist = (unsigned int*)As;          // [128][8]
    float* psum = (float*)(As + 1024);               // [128][16]
    for (int i = t; i < 1024; i += 256) hist[i] = 0u;
    __syncthreads();
    #pragma unroll
    for (int i = 0; i < 8; ++i) {
        int lr = ty * 8 + i;
        float s = 0.f;
        #pragma unroll
        for (int j = 0; j < 8; ++j) {
            int gc = cbase + tx * 8 + j;
            if (gc < PN) {
                float v = acc[i][j];
                s += expf(v);
                int b = 7;
                b = v >= 0.20f ? 6 : b;
                b = v >= 0.24f ? 5 : b;
                b = v >= 0.28f ? 4 : b;
                b = v >= 0.32f ? 3 : b;
                b = v >= 0.36f ? 2 : b;
                b = v >= 0.40f ? 1 : b;
                b = v >= 0.44f ? 0 : b;
                atomicAdd(&hist[lr * 8 + b], 1u);
            }
        }
        psum[lr * 16 + tx] = s;
    }
    __syncthreads();
    if (t < 128) {
        int row = rbase + t;
        float s = 0.f;
        #pragma unroll
        for (int x = 0; x < 16; ++x) s += psum[t * 16 + x];
        gsum[(size_t)row * NCB + bx] = s;
        #pragma unroll
        for (int b = 0; b < 8; ++b) {
            unsigned int h = hist[t * 8 + b];
            if (h) atomicAdd(&ghist[row * 8 + b], h);
        }
    }
}

// ---------------- K3v2: threshold from hist, single compact pass, sort, emit ----------------
__global__ __launch_bounds__(1024) void k3v2(
    const float* __restrict__ logits, const unsigned int* __restrict__ ghist,
    const float* __restrict__ gsum, const int* __restrict__ nin,
    float* __restrict__ srted, int* __restrict__ sidx,
    float* __restrict__ maskp, float* __restrict__ nrp)
{
    __shared__ float s_T;
    __shared__ float s_inv;
    __shared__ unsigned int ccnt;
    __shared__ float wsum[16];
    __shared__ unsigned int ckey[CAP];
    __shared__ unsigned int cidx[CAP];
    __shared__ unsigned long long arr[CAP];

    int r = blockIdx.x;
    int t = threadIdx.x;
    if (t == 0) {
        const float edges[8] = {0.44f, 0.40f, 0.36f, 0.32f, 0.28f, 0.24f, 0.20f, -3.0f};
        unsigned int cum = 0; int cb = 7;
        for (int b = 0; b < 8; ++b) {
            cum += ghist[r * 8 + b];
            if (cum >= 128u) { cb = b; break; }
        }
        s_T = edges[cb];
        ccnt = 0u;
    }
    // deterministic expsum: fixed slots, fixed reduction tree
    float es = 0.f;
    for (int i = t; i < NCB; i += 1024) es += gsum[(size_t)r * NCB + i];
    #pragma unroll
    for (int off = 32; off > 0; off >>= 1) es += __shfl_xor(es, off);
    if ((t & 63) == 0) wsum[t >> 6] = es;
    __syncthreads();
    if (t == 0) {
        float s = 0.f;
        for (int i = 0; i < 16; ++i) s += wsum[i];
        s_inv = 1.0f / s;
    }
    __syncthreads();
    float T = s_T;
    const float4* row4 = (const float4*)(logits + (size_t)r * PN);
    for (int i = t; i < PN / 4; i += 1024) {
        float4 v = row4[i];
        if (v.x >= T) { unsigned int p = atomicAdd(&ccnt, 1u); if (p < CAP) { ckey[p] = sortkey(v.x); cidx[p] = 4 * i + 0; } }
        if (v.y >= T) { unsigned int p = atomicAdd(&ccnt, 1u); if (p < CAP) { ckey[p] = sortkey(v.y); cidx[p] = 4 * i + 1; } }
        if (v.z >= T) { unsigned int p = atomicAdd(&ccnt, 1u); if (p < CAP) { ckey[p] = sortkey(v.z); cidx[p] = 4 * i + 2; } }
        if (v.w >= T) { unsigned int p = atomicAdd(&ccnt, 1u); if (p < CAP) { ckey[p] = sortkey(v.w); cidx[p] = 4 * i + 3; } }
    }
    __syncthreads();
    int nc = (int)min(ccnt, (unsigned int)CAP);
    int P = 128;
    while (P < nc) P <<= 1;
    for (int i = t; i < P; i += 1024)
        arr[i] = (i < nc) ? ((((unsigned long long)ckey[i]) << 32) | (unsigned int)(~cidx[i])) : 0ull;
    __syncthreads();
    for (int kk = 2; kk <= P; kk <<= 1) {
        for (int j = kk >> 1; j > 0; j >>= 1) {
            for (int i = t; i < P; i += 1024) {
                int l = i ^ j;
                if (l > i) {
                    unsigned long long a = arr[i], b = arr[l];
                    bool up = ((i & kk) == 0);
                    if (up ? (a < b) : (a > b)) { arr[i] = b; arr[l] = a; }
                }
            }
            __syncthreads();
        }
    }
    int nr = nin[r]; nr = nr < 1 ? 1 : (nr > 128 ? 128 : nr);
    if (t < 128) {
        unsigned long long c = arr[t];
        unsigned int key = (unsigned int)(c >> 32);
        unsigned int idx = ~((unsigned int)c);
        unsigned int u = (key & 0x80000000u) ? (key ^ 0x80000000u) : ~key;
        float v = __uint_as_float(u);
        srted[r * 128 + t] = expf(v) * s_inv;
        sidx[r * 128 + t] = (int)idx;
        maskp[r * 128 + t] = (t < nr) ? 1.0f : 0.0f;
    }
    if (t == 0) nrp[r] = (float)nr;
}

// ---------------- combined W transpose+convert ----------------
__global__ __launch_bounds__(256) void k_wconv_all(
    const float* __restrict__ ow1, const float* __restrict__ ow2, const float* __restrict__ ow3,
    f16* __restrict__ W1t, f16* __restrict__ W2t, f16* __restrict__ W3t)
{
    int idx = blockIdx.x * 256 + threadIdx.x;
    if (idx < 262144) {
        int n = idx >> 9, k = idx & 511;
        W1t[idx] = (f16)ow1[(size_t)k * 512 + n];
    } else if (idx < 393216) {
        int j = idx - 262144;
        int n = j >> 9, k = j & 511;
        W2t[j] = (f16)ow2[(size_t)k * 256 + n];
    } else {
        int j = idx - 393216;
        int n = j >> 8, k = j & 255;
        W3t[j] = (f16)ow3[(size_t)k * 256 + n];
    }
}

// ---------------- Build X1[32768][512] f16 ----------------
__global__ __launch_bounds__(256) void k_buildx(
    const float* __restrict__ points, const float* __restrict__ latent,
    const float* __restrict__ srted, const int* __restrict__ sidx,
    const float* __restrict__ l1w, const float* __restrict__ l1b,
    const float* __restrict__ l2w, const float* __restrict__ l2b,
    f16* __restrict__ X1)
{
    __shared__ float s_s[16];
    __shared__ int s_pi[16];
    int t = threadIdx.x;
    int tok0 = blockIdx.x * 16;
    if (t < 16) {
        int token = tok0 + t;
        s_s[t] = 128.0f * srted[token];
        s_pi[t] = sidx[token];
    }
    __syncthreads();
    float w1 = l1w[t], b1 = l1b[t], w2 = l2w[t], b2 = l2b[t];
    for (int tt = 0; tt < 16; ++tt) {
        int token = tok0 + tt;
        int b = token >> 7;
        float s = s_s[tt];
        float p = points[(size_t)s_pi[tt] * 256 + t];
        float alpha = fmaf(s, w1, b1);
        float beta = fmaf(s, w2, b2);
        X1[(size_t)token * 512 + t] = (f16)fmaf(alpha, p, beta);
        X1[(size_t)token * 512 + 256 + t] = (f16)latent[b * 256 + t];
    }
}

// ---------------- f16 MFMA GEMM ----------------
template<int RELU, int OUT_F16>
__global__ __launch_bounds__(256) void gemm_tn(
    const f16* __restrict__ A, const f16* __restrict__ Bt,
    const float* __restrict__ bias,
    f16* __restrict__ Cf16, float* __restrict__ Cf32,
    int N, int K)
{
    __shared__ __align__(16) f16 As[128 * 64];
    __shared__ __align__(16) f16 Bs[128 * 64];
    int tid = threadIdx.x;
    int lane = tid & 63, wave = tid >> 6;
    int brow = blockIdx.y * 128;
    int bcol = blockIdx.x * 128;
    int wr = wave >> 1, wc = wave & 1;

    f32x4 acc[4][4] = {};

    int b_off = tid * 16;
    int sr = b_off >> 7;
    int soff = b_off & 127;
    char* ldsA = (char*)As + wave * 1024;
    char* ldsB = (char*)Bs + wave * 1024;

    for (int kt = 0; kt < K; kt += 64) {
        #pragma unroll
        for (int c = 0; c < 4; ++c) {
            int r = sr + c * 32;
            const char* ga = (const char*)A + ((size_t)(brow + r) * K + kt) * 2 + soff;
            gload_lds16(ga, ldsA + c * 4096);
        }
        #pragma unroll
        for (int c = 0; c < 4; ++c) {
            int r = sr + c * 32;
            const char* gb = (const char*)Bt + ((size_t)(bcol + r) * K + kt) * 2 + soff;
            gload_lds16(gb, ldsB + c * 4096);
        }
        __syncthreads();
        #pragma unroll
        for (int ks = 0; ks < 2; ++ks) {
            f16x8 af[4], bf[4];
            int kk = ks * 32 + (lane >> 4) * 8;
            #pragma unroll
            for (int i = 0; i < 4; ++i) {
                int row = wr * 64 + i * 16 + (lane & 15);
                af[i] = *(const f16x8*)&As[row * 64 + kk];
                int col = wc * 64 + i * 16 + (lane & 15);
                bf[i] = *(const f16x8*)&Bs[col * 64 + kk];
            }
            #pragma unroll
            for (int i = 0; i < 4; ++i)
                #pragma unroll
                for (int j = 0; j < 4; ++j)
                    acc[i][j] = __builtin_amdgcn_mfma_f32_16x16x32_f16(af[i], bf[j], acc[i][j], 0, 0, 0);
        }
        __syncthreads();
    }

    #pragma unroll
    for (int i = 0; i < 4; ++i) {
        int row = brow + wr * 64 + i * 16 + (lane >> 4) * 4;
        #pragma unroll
        for (int j = 0; j < 4; ++j) {
            int col = bcol + wc * 64 + j * 16 + (lane & 15);
            float bz = bias[col];
            #pragma unroll
            for (int r2 = 0; r2 < 4; ++r2) {
                float v = acc[i][j][r2] + bz;
                if (RELU) v = fmaxf(v, 0.f);
                if (OUT_F16) Cf16[(size_t)(row + r2) * N + col] = (f16)v;
                else         Cf32[(size_t)(row + r2) * N + col] = v;
            }
        }
    }
}

extern "C" void kernel_launch(void* const* d_in, const int* in_sizes, int n_in,
                              void* d_out, int out_size, void* d_ws, size_t ws_size,
                              hipStream_t stream) {
    (void)in_sizes; (void)n_in; (void)out_size; (void)ws_size;
    const float* latent = (const float*)d_in[0];
    const int*   nin    = (const int*)d_in[1];
    const float* points = (const float*)d_in[2];
    const float* ap     = (const float*)d_in[3];
    const float* aw1 = (const float*)d_in[4];  const float* ab1 = (const float*)d_in[5];
    const float* aw2 = (const float*)d_in[6];  const float* ab2 = (const float*)d_in[7];
    const float* aw3 = (const float*)d_in[8];  const float* ab3 = (const float*)d_in[9];
    const float* aw4 = (const float*)d_in[10]; const float* ab4 = (const float*)d_in[11];
    const float* l1w = (const float*)d_in[12]; const float* l1b = (const float*)d_in[13];
    const float* l2w = (const float*)d_in[14]; const float* l2b = (const float*)d_in[15];
    const float* ow1 = (const float*)d_in[16]; const float* ob1 = (const float*)d_in[17];
    const float* ow2 = (const float*)d_in[18]; const float* ob2 = (const float*)d_in[19];
    const float* ow3 = (const float*)d_in[20]; const float* ob3 = (const float*)d_in[21];

    char* wsb = (char*)d_ws;
    float* ang   = (float*)wsb;                 // 64 KB
    float* srted = (float*)(wsb + 65536);       // 128 KB
    int*   sidx  = (int*)(wsb + 196608);        // 128 KB
    float* logit = (float*)(wsb + 327680);      // 102.4 MB

    char* lz = wsb + 327680;
    float* h1 = (float*)lz;
    float* h2 = (float*)(lz + 524288);
    float* h3 = (float*)(lz + 1048576);
    f16* X1  = (f16*)lz;
    f16* H1  = (f16*)(lz + 33554432);
    f16* H2  = (f16*)(lz + 67108864);
    f16* W1t = (f16*)(lz + 83886080);
    f16* W2t = (f16*)(lz + 84410368);
    f16* W3t = (f16*)(lz + 84672512);

    float* outp  = (float*)d_out;               // [32768][256]
    float* maskp = outp + 8388608;
    float* nrp   = outp + 8421376;

    // gsum/ghist live in d_out's scratch window (dead until k3/G3 overwrite it)
    float* gsum = outp;                                  // 256*782*4 = 800768 B
    unsigned int* ghist = (unsigned int*)(outp + 262144); // @1 MB, 8 KB

    hipLaunchKernelGGL(k1_layer, dim3(8, 8), dim3(256), 0, stream, latent, aw1, ab1, h1, 512, 256);
    hipLaunchKernelGGL(k1_layer, dim3(8, 8), dim3(256), 0, stream, h1, aw2, ab2, h2, 512, 512);
    hipLaunchKernelGGL(k1_layer, dim3(8, 8), dim3(256), 0, stream, h2, aw3, ab3, h3, 512, 512);
    hipLaunchKernelGGL(k1_final, dim3(8), dim3(256), 0, stream, h3, aw4, ab4, ang);
    hipMemsetAsync(ghist, 0, 256 * 8 * sizeof(unsigned int), stream);
    hipLaunchKernelGGL(k2v2, dim3(NCB, 2), dim3(256), 0, stream,
                       ang, ap, logit, ghist, gsum);
    hipLaunchKernelGGL(k3v2, dim3(256), dim3(1024), 0, stream,
                       logit, ghist, gsum, nin, srted, sidx, maskp, nrp);
    hipLaunchKernelGGL(k_wconv_all, dim3(1792), dim3(256), 0, stream, ow1, ow2, ow3, W1t, W2t, W3t);
    hipLaunchKernelGGL(k_buildx, dim3(2048), dim3(256), 0, stream,
                       points, latent, srted, sidx, l1w, l1b, l2w, l2b, X1);
    hipLaunchKernelGGL((gemm_tn<1, 1>), dim3(4, 256), dim3(256), 0, stream,
                       X1, W1t, ob1, H1, (float*)nullptr, 512, 512);
    hipLaunchKernelGGL((gemm_tn<1, 1>), dim3(2, 256), dim3(256), 0, stream,
                       H1, W2t, ob2, H2, (float*)nullptr, 256, 512);
    hipLaunchKernelGGL((gemm_tn<0, 0>), dim3(2, 256), dim3(256), 0, stream,
                       H2, W3t, ob3, (f16*)nullptr, outp, 256, 256);
}